// Round 16
// baseline (134.725 us; speedup 1.0000x reference)
//
#include <hip/hip_runtime.h>
#include <hip/hip_bf16.h>
#include <math.h>

#define N_NODES 50000
#define E_EDGES 800000
#define IN_DIM  128
#define HID     64
#define KF      4
#define EXP_HID 64

// d_out layout (float32, concatenated in return order):
//   disen_graph_emb (K*HID = 256) | Z (N*K*HID = 12,800,000) |
//   e_h_final (E = 800,000)       | e_h_all (K*E = 3,200,000)
#define OFF_DISEN 0
#define OFF_Z     (KF*HID)
#define OFF_EHF   (OFF_Z + N_NODES*KF*HID)
#define OFF_EHALL (OFF_EHF + E_EDGES)

#define NROWS (N_NODES * KF)     // 200000 (n,k) rows
#define EPW 64                   // edges per wave in edge_kernel7
#define PIPE 8                   // software-pipeline depth (edges in flight)

typedef __bf16 bf16x8 __attribute__((ext_vector_type(8)));
typedef float  f32x4  __attribute__((ext_vector_type(4)));
typedef unsigned short ushort_t;
typedef unsigned int   uint_t;

// ---------------------------------------------------------------------------
// prep (r12 verbatim): 41 blocks. 0-31: Wz swizzle; 32-39: Wpq swizzle;
// 40: disen init.
// ---------------------------------------------------------------------------
__global__ __launch_bounds__(256) void prep_kernel(
    const float* __restrict__ W, const float* __restrict__ W1,
    float* __restrict__ disen, __bf16* __restrict__ Wz,
    __bf16* __restrict__ Wpq) {
  const int b = blockIdx.x, tid = threadIdx.x;
  if (b < 32) {
#pragma unroll
    for (int i = 0; i < 4; ++i) {
      const int idx = (b * 4 + i) * 256 + tid;    // k*8192 + ii*64 + h
      const int k  = idx >> 13;
      const int ii = (idx >> 6) & 127;
      const int h  = idx & 63;
      const int col = k * 64 + h;
      const int t = col >> 4, c = col & 15;
      const int kh = ii >> 5, g = (ii >> 3) & 3, e = ii & 7;
      Wz[((t * 4 + kh) * 4 + g) * 128 + c * 8 + e] = (__bf16)W[idx];
    }
  } else if (b < 40) {
#pragma unroll
    for (int i = 0; i < 4; ++i) {
      const int idx = ((b - 32) * 4 + i) * 256 + tid;   // r*64 + cc
      const int r = idx >> 6, cc = idx & 63;
      const int k = (r < 64) ? r : (r - 64);
      const int j = (r < 64) ? cc : (64 + cc);
      const int t = j >> 4, c = j & 15;
      const int kh = k >> 5, g = (k >> 3) & 3, e = k & 7;
      Wpq[((t * 2 + kh) * 4 + g) * 128 + c * 8 + e] = (__bf16)W1[idx];
    }
  } else {
    disen[tid] = 0.f;
  }
}

// ---------------------------------------------------------------------------
// z via MFMA (r13 verbatim, k-phased). Measured-good.
// ---------------------------------------------------------------------------
__global__ __launch_bounds__(256) void z_mfma_kernel2(
    const float* __restrict__ x, const float* __restrict__ b_init,
    const __bf16* __restrict__ Wz, float* __restrict__ out) {
  __shared__ float dred[4][256];
  const int tid = threadIdx.x;
  const int w = tid >> 6, l = tid & 63;
  const int lg = l >> 4, lc = l & 15;
  const int n0 = blockIdx.x * 64;
  const int ra = min(n0 + w * 16 + lc, N_NODES - 1);   // A row (clamped tail)

  bf16x8 af[4];
#pragma unroll
  for (int kh = 0; kh < 4; ++kh) {
    const float4* xp = (const float4*)(x + (size_t)ra * IN_DIM + kh * 32 + lg * 8);
    const float4 f0 = xp[0], f1 = xp[1];
    bf16x8 a;
    a[0] = (__bf16)f0.x; a[1] = (__bf16)f0.y;
    a[2] = (__bf16)f0.z; a[3] = (__bf16)f0.w;
    a[4] = (__bf16)f1.x; a[5] = (__bf16)f1.y;
    a[6] = (__bf16)f1.z; a[7] = (__bf16)f1.w;
    af[kh] = a;
  }

#pragma unroll 1
  for (int k = 0; k < KF; ++k) {
    f32x4 acc[4];
#pragma unroll
    for (int tt = 0; tt < 4; ++tt) acc[tt] = (f32x4){0.f, 0.f, 0.f, 0.f};

#pragma unroll
    for (int tt = 0; tt < 4; ++tt)
#pragma unroll
      for (int kh = 0; kh < 4; ++kh) {
        const bf16x8 bf = *(const bf16x8*)(
            Wz + (((k * 4 + tt) * 4 + kh) * 4 + lg) * 128 + lc * 8);
        acc[tt] = __builtin_amdgcn_mfma_f32_16x16x32_bf16(af[kh], bf, acc[tt],
                                                          0, 0, 0);
      }

    float vals[4][4];
#pragma unroll
    for (int tt = 0; tt < 4; ++tt) {
      const float bias = b_init[(k * 4 + tt) * 16 + lc];
#pragma unroll
      for (int r = 0; r < 4; ++r)
        vals[tt][r] = fmaxf(acc[tt][r] + bias, 0.f);
    }
    float s[4];
#pragma unroll
    for (int r = 0; r < 4; ++r)
      s[r] = vals[0][r] * vals[0][r] + vals[1][r] * vals[1][r] +
             vals[2][r] * vals[2][r] + vals[3][r] * vals[3][r];
#pragma unroll
    for (int d = 1; d < 16; d <<= 1)
#pragma unroll
      for (int r = 0; r < 4; ++r) s[r] += __shfl_xor(s[r], d, 64);
    float rn[4];
#pragma unroll
    for (int r = 0; r < 4; ++r)
      rn[r] = 1.f / fmaxf(sqrtf(s[r]), 1e-12f);

#pragma unroll
    for (int tt = 0; tt < 4; ++tt) {
      const int col = k * 64 + tt * 16 + lc;
      float dmt = 0.f;
#pragma unroll
      for (int r = 0; r < 4; ++r) {
        const float zn = vals[tt][r] * rn[r];
        const int node = n0 + w * 16 + lg * 4 + r;
        if (node < N_NODES)
          out[OFF_Z + (size_t)node * (KF * HID) + col] = zn;
        dmt = fmaxf(dmt, zn);
      }
      dmt = fmaxf(dmt, __shfl_xor(dmt, 16, 64));
      dmt = fmaxf(dmt, __shfl_xor(dmt, 32, 64));
      if (lg == 0) dred[w][col] = dmt;
    }
  }
  __syncthreads();
  {
    const float m = fmaxf(fmaxf(dred[0][tid], dred[1][tid]),
                          fmaxf(dred[2][tid], dred[3][tid]));
    atomicMax((unsigned int*)(out + OFF_DISEN + tid), __float_as_uint(m));
  }
}

// ---------------------------------------------------------------------------
// pq via MFMA -> biased-uint8 P/Q with per-row scales (r15 verbatim).
// Row layout byte[lc*4+t] = col[t*16+lc] (fixed permutation; W2 matched).
// ---------------------------------------------------------------------------
__global__ __launch_bounds__(256) void pq_mfma_kernel3(
    const float* __restrict__ Z, const float* __restrict__ b1,
    const __bf16* __restrict__ Wpq, unsigned char* __restrict__ P8,
    unsigned char* __restrict__ Q8, float* __restrict__ Psc,
    float* __restrict__ Qsc) {
  const int tid = threadIdx.x;
  const int w = tid >> 6, l = tid & 63;
  const int lg = l >> 4, lc = l & 15;
  const int base = blockIdx.x * 64;              // exact: 3125*64 = 200000
  const int rowA = base + w * 16 + lc;

  bf16x8 af[2];
#pragma unroll
  for (int kh = 0; kh < 2; ++kh) {
    const float4* zp = (const float4*)(Z + (size_t)rowA * HID + kh * 32 + lg * 8);
    const float4 f0 = zp[0], f1 = zp[1];
    bf16x8 a;
    a[0] = (__bf16)f0.x; a[1] = (__bf16)f0.y;
    a[2] = (__bf16)f0.z; a[3] = (__bf16)f0.w;
    a[4] = (__bf16)f1.x; a[5] = (__bf16)f1.y;
    a[6] = (__bf16)f1.z; a[7] = (__bf16)f1.w;
    af[kh] = a;
  }

  f32x4 acc[8];
#pragma unroll
  for (int t = 0; t < 8; ++t) acc[t] = (f32x4){0.f, 0.f, 0.f, 0.f};

#pragma unroll
  for (int t = 0; t < 8; ++t)
#pragma unroll
    for (int kh = 0; kh < 2; ++kh) {
      const bf16x8 bf =
          *(const bf16x8*)(Wpq + ((t * 2 + kh) * 4 + lg) * 128 + lc * 8);
      acc[t] = __builtin_amdgcn_mfma_f32_16x16x32_bf16(af[kh], bf, acc[t],
                                                       0, 0, 0);
    }

  float pvv[4][4], qvv[4][4];
#pragma unroll
  for (int t = 0; t < 4; ++t) {
    const float bias = b1[t * 16 + lc];
#pragma unroll
    for (int r = 0; r < 4; ++r) {
      pvv[t][r] = acc[t][r] + bias;
      qvv[t][r] = acc[t + 4][r];
    }
  }

#pragma unroll
  for (int r = 0; r < 4; ++r) {
    float pm = fmaxf(fmaxf(fabsf(pvv[0][r]), fabsf(pvv[1][r])),
                     fmaxf(fabsf(pvv[2][r]), fabsf(pvv[3][r])));
    float qm = fmaxf(fmaxf(fabsf(qvv[0][r]), fabsf(qvv[1][r])),
                     fmaxf(fabsf(qvv[2][r]), fabsf(qvv[3][r])));
#pragma unroll
    for (int d = 1; d < 16; d <<= 1) {           // 16-lane row reduce
      pm = fmaxf(pm, __shfl_xor(pm, d, 64));
      qm = fmaxf(qm, __shfl_xor(qm, d, 64));
    }
    pm = fmaxf(pm, 1e-12f);
    qm = fmaxf(qm, 1e-12f);
    const float pinv = 127.f / pm, qinv = 127.f / qm;

    uint_t packP = 0, packQ = 0;
#pragma unroll
    for (int t = 0; t < 4; ++t) {
      const int qp = __float2int_rn(pvv[t][r] * pinv) + 128;  // biased uint8
      const int qq = __float2int_rn(qvv[t][r] * qinv) + 128;
      packP |= (uint_t)(qp & 0xff) << (8 * t);
      packQ |= (uint_t)(qq & 0xff) << (8 * t);
    }
    const int grow = base + w * 16 + lg * 4 + r;
    *(uint_t*)(P8 + (size_t)grow * 64 + lc * 4) = packP;
    *(uint_t*)(Q8 + (size_t)grow * 64 + lc * 4) = packQ;
    if (lc == 0) {
      Psc[grow] = pm * (1.f / 127.f);
      Qsc[grow] = qm * (1.f / 127.f);
    }
  }
}

// ---------------------------------------------------------------------------
// Edge kernel v7: r15 structure with PIPE=8 (was 4). Rationale: bf16 edge4
// sustained 3.35 TB/s scatter with 64 lines in flight/wave; int8 edge6 held
// only ~40 lines -> 2.66 TB/s (latency-bound, not VALU). 8 edges in flight
// -> ~80 lines/wave outstanding.
// ---------------------------------------------------------------------------
__global__ __launch_bounds__(256) void edge_kernel7(
    const int* __restrict__ ei, const float* __restrict__ W2,
    const float* __restrict__ b2, const unsigned char* __restrict__ P8,
    const unsigned char* __restrict__ Q8, const float* __restrict__ Psc,
    const float* __restrict__ Qsc, float* __restrict__ ehf,
    float* __restrict__ ehall) {
  __shared__ float tile[4][KF][EPW + 1];           // pad: k-stride 65
  const int tid = threadIdx.x;
  const int w = tid >> 6;
  const int lane = tid & 63;
  const int lc = lane & 15, lk = lane >> 4;
  const int eb = blockIdx.x * 256 + w * EPW;       // this wave's 64 edges

  // lane's 4 W2 coefs for orig cols {t*16+lc}
  const float w2a = W2[lc],      w2b = W2[16 + lc];
  const float w2c = W2[32 + lc], w2d = W2[48 + lc];
  const float bias2 = b2[0];

  const int srcl = ei[eb + lane];                  // coalesced
  const int dstl = ei[E_EDGES + eb + lane];

  uint_t pv[PIPE], qv[PIPE];
  float ps[PIPE], qs[PIPE];
#pragma unroll
  for (int d = 0; d < PIPE; ++d) {
    const int s = __shfl(srcl, d, 64);             // readlane -> SGPR base
    const int t = __shfl(dstl, d, 64);
    pv[d] = *(const uint_t*)(P8 + (size_t)s * 256 + lane * 4);
    qv[d] = *(const uint_t*)(Q8 + (size_t)t * 256 + lane * 4);
    ps[d] = Psc[s * 4 + lk];
    qs[d] = Qsc[t * 4 + lk];
  }

#pragma unroll
  for (int i = 0; i < EPW; ++i) {
    const uint_t p = pv[i & (PIPE - 1)], q = qv[i & (PIPE - 1)];
    const float pss = ps[i & (PIPE - 1)], qss = qs[i & (PIPE - 1)];
    if (i + PIPE < EPW) {                          // static under full unroll
      const int s = __shfl(srcl, i + PIPE, 64);
      const int t = __shfl(dstl, i + PIPE, 64);
      pv[i & (PIPE - 1)] = *(const uint_t*)(P8 + (size_t)s * 256 + lane * 4);
      qv[i & (PIPE - 1)] = *(const uint_t*)(Q8 + (size_t)t * 256 + lane * 4);
      ps[i & (PIPE - 1)] = Psc[s * 4 + lk];
      qs[i & (PIPE - 1)] = Qsc[t * 4 + lk];
    }
    const float c = -128.f * (pss + qss);          // bias fold, 2 ops/4 elems

    // ubyte unpack: single v_cvt_f32_ubyteN each
    const float p0 = (float)(p & 0xffu);
    const float p1 = (float)((p >> 8) & 0xffu);
    const float p2 = (float)((p >> 16) & 0xffu);
    const float p3 = (float)(p >> 24);
    const float q0 = (float)(q & 0xffu);
    const float q1 = (float)((q >> 8) & 0xffu);
    const float q2 = (float)((q >> 16) & 0xffu);
    const float q3 = (float)(q >> 24);

    float s4 = fmaxf(fmaf(p0, pss, fmaf(q0, qss, c)), 0.f) * w2a;
    s4 = fmaf(fmaxf(fmaf(p1, pss, fmaf(q1, qss, c)), 0.f), w2b, s4);
    s4 = fmaf(fmaxf(fmaf(p2, pss, fmaf(q2, qss, c)), 0.f), w2c, s4);
    s4 = fmaf(fmaxf(fmaf(p3, pss, fmaf(q3, qss, c)), 0.f), w2d, s4);

    // sum the 16 lanes of this k-group
    s4 += __shfl_xor(s4, 1, 64);
    s4 += __shfl_xor(s4, 2, 64);
    s4 += __shfl_xor(s4, 4, 64);
    s4 += __shfl_xor(s4, 8, 64);
    if (lc == 0) tile[w][lk][i] = s4 + bias2;
  }
  __syncthreads();

  const float v0 = tile[w][0][lane];
  const float v1 = tile[w][1][lane];
  const float v2 = tile[w][2][lane];
  const float v3 = tile[w][3][lane];
  ehall[(size_t)0 * E_EDGES + eb + lane] = v0;     // coalesced per wave
  ehall[(size_t)1 * E_EDGES + eb + lane] = v1;
  ehall[(size_t)2 * E_EDGES + eb + lane] = v2;
  ehall[(size_t)3 * E_EDGES + eb + lane] = v3;
  ehf[eb + lane] = fmaxf(fmaxf(v0, v1), fmaxf(v2, v3));
}

// ---------------------------------------------------------------------------
extern "C" void kernel_launch(void* const* d_in, const int* in_sizes, int n_in,
                              void* d_out, int out_size, void* d_ws,
                              size_t ws_size, hipStream_t stream) {
  const float* x      = (const float*)d_in[0];
  const int*   ei     = (const int*)  d_in[1];
  const float* W_init = (const float*)d_in[2];
  const float* b_init = (const float*)d_in[3];
  const float* W1     = (const float*)d_in[4];
  const float* b1     = (const float*)d_in[5];
  const float* W2     = (const float*)d_in[6];
  const float* b2     = (const float*)d_in[7];
  float* out = (float*)d_out;

  // d_ws: P8 (12.8MB) | Q8 (12.8MB) | Psc (0.8MB) | Qsc (0.8MB) |
  //       Wz (64KB) | Wpq (16KB).  Total ~27.3MB << ws_size.
  unsigned char* P8 = (unsigned char*)d_ws;
  unsigned char* Q8 = P8 + (size_t)NROWS * 64;
  float* Psc = (float*)(Q8 + (size_t)NROWS * 64);
  float* Qsc = Psc + NROWS;
  __bf16* Wz  = (__bf16*)(Qsc + NROWS);
  __bf16* Wpq = Wz + 32768;

  prep_kernel<<<41, 256, 0, stream>>>(W_init, W1, out + OFF_DISEN, Wz, Wpq);
  z_mfma_kernel2<<<(N_NODES + 63) / 64, 256, 0, stream>>>(
      x, b_init, Wz, out);
  pq_mfma_kernel3<<<NROWS / 64, 256, 0, stream>>>(
      out + OFF_Z, b1, Wpq, P8, Q8, Psc, Qsc);
  edge_kernel7<<<E_EDGES / 256, 256, 0, stream>>>(
      ei, W2, b2, P8, Q8, Psc, Qsc, out + OFF_EHF, out + OFF_EHALL);
}

// Round 17
// 128.522 us; speedup vs baseline: 1.0483x; 1.0483x over previous
//
#include <hip/hip_runtime.h>
#include <hip/hip_bf16.h>
#include <math.h>

#define N_NODES 50000
#define E_EDGES 800000
#define IN_DIM  128
#define HID     64
#define KF      4
#define EXP_HID 64

// d_out layout (float32, concatenated in return order):
//   disen_graph_emb (K*HID = 256) | Z (N*K*HID = 12,800,000) |
//   e_h_final (E = 800,000)       | e_h_all (K*E = 3,200,000)
#define OFF_DISEN 0
#define OFF_Z     (KF*HID)
#define OFF_EHF   (OFF_Z + N_NODES*KF*HID)
#define OFF_EHALL (OFF_EHF + E_EDGES)

#define NROWS (N_NODES * KF)     // 200000 (n,k) rows
#define EPW 64                   // edges per wave
#define EPIPE 4                  // pipeline depth in 4-edge steps

typedef __bf16 bf16x8 __attribute__((ext_vector_type(8)));
typedef float  f32x4  __attribute__((ext_vector_type(4)));
typedef unsigned short ushort_t;
typedef unsigned int   uint_t;

// ---------------------------------------------------------------------------
// prep (r12 verbatim): 41 blocks. 0-31: Wz swizzle; 32-39: Wpq swizzle;
// 40: disen init.
// ---------------------------------------------------------------------------
__global__ __launch_bounds__(256) void prep_kernel(
    const float* __restrict__ W, const float* __restrict__ W1,
    float* __restrict__ disen, __bf16* __restrict__ Wz,
    __bf16* __restrict__ Wpq) {
  const int b = blockIdx.x, tid = threadIdx.x;
  if (b < 32) {
#pragma unroll
    for (int i = 0; i < 4; ++i) {
      const int idx = (b * 4 + i) * 256 + tid;    // k*8192 + ii*64 + h
      const int k  = idx >> 13;
      const int ii = (idx >> 6) & 127;
      const int h  = idx & 63;
      const int col = k * 64 + h;
      const int t = col >> 4, c = col & 15;
      const int kh = ii >> 5, g = (ii >> 3) & 3, e = ii & 7;
      Wz[((t * 4 + kh) * 4 + g) * 128 + c * 8 + e] = (__bf16)W[idx];
    }
  } else if (b < 40) {
#pragma unroll
    for (int i = 0; i < 4; ++i) {
      const int idx = ((b - 32) * 4 + i) * 256 + tid;   // r*64 + cc
      const int r = idx >> 6, cc = idx & 63;
      const int k = (r < 64) ? r : (r - 64);
      const int j = (r < 64) ? cc : (64 + cc);
      const int t = j >> 4, c = j & 15;
      const int kh = k >> 5, g = (k >> 3) & 3, e = k & 7;
      Wpq[((t * 2 + kh) * 4 + g) * 128 + c * 8 + e] = (__bf16)W1[idx];
    }
  } else {
    disen[tid] = 0.f;
  }
}

// ---------------------------------------------------------------------------
// z via MFMA (r13 verbatim, k-phased). Measured-good.
// ---------------------------------------------------------------------------
__global__ __launch_bounds__(256) void z_mfma_kernel2(
    const float* __restrict__ x, const float* __restrict__ b_init,
    const __bf16* __restrict__ Wz, float* __restrict__ out) {
  __shared__ float dred[4][256];
  const int tid = threadIdx.x;
  const int w = tid >> 6, l = tid & 63;
  const int lg = l >> 4, lc = l & 15;
  const int n0 = blockIdx.x * 64;
  const int ra = min(n0 + w * 16 + lc, N_NODES - 1);   // A row (clamped tail)

  bf16x8 af[4];
#pragma unroll
  for (int kh = 0; kh < 4; ++kh) {
    const float4* xp = (const float4*)(x + (size_t)ra * IN_DIM + kh * 32 + lg * 8);
    const float4 f0 = xp[0], f1 = xp[1];
    bf16x8 a;
    a[0] = (__bf16)f0.x; a[1] = (__bf16)f0.y;
    a[2] = (__bf16)f0.z; a[3] = (__bf16)f0.w;
    a[4] = (__bf16)f1.x; a[5] = (__bf16)f1.y;
    a[6] = (__bf16)f1.z; a[7] = (__bf16)f1.w;
    af[kh] = a;
  }

#pragma unroll 1
  for (int k = 0; k < KF; ++k) {
    f32x4 acc[4];
#pragma unroll
    for (int tt = 0; tt < 4; ++tt) acc[tt] = (f32x4){0.f, 0.f, 0.f, 0.f};

#pragma unroll
    for (int tt = 0; tt < 4; ++tt)
#pragma unroll
      for (int kh = 0; kh < 4; ++kh) {
        const bf16x8 bf = *(const bf16x8*)(
            Wz + (((k * 4 + tt) * 4 + kh) * 4 + lg) * 128 + lc * 8);
        acc[tt] = __builtin_amdgcn_mfma_f32_16x16x32_bf16(af[kh], bf, acc[tt],
                                                          0, 0, 0);
      }

    float vals[4][4];
#pragma unroll
    for (int tt = 0; tt < 4; ++tt) {
      const float bias = b_init[(k * 4 + tt) * 16 + lc];
#pragma unroll
      for (int r = 0; r < 4; ++r)
        vals[tt][r] = fmaxf(acc[tt][r] + bias, 0.f);
    }
    float s[4];
#pragma unroll
    for (int r = 0; r < 4; ++r)
      s[r] = vals[0][r] * vals[0][r] + vals[1][r] * vals[1][r] +
             vals[2][r] * vals[2][r] + vals[3][r] * vals[3][r];
#pragma unroll
    for (int d = 1; d < 16; d <<= 1)
#pragma unroll
      for (int r = 0; r < 4; ++r) s[r] += __shfl_xor(s[r], d, 64);
    float rn[4];
#pragma unroll
    for (int r = 0; r < 4; ++r)
      rn[r] = 1.f / fmaxf(sqrtf(s[r]), 1e-12f);

#pragma unroll
    for (int tt = 0; tt < 4; ++tt) {
      const int col = k * 64 + tt * 16 + lc;
      float dmt = 0.f;
#pragma unroll
      for (int r = 0; r < 4; ++r) {
        const float zn = vals[tt][r] * rn[r];
        const int node = n0 + w * 16 + lg * 4 + r;
        if (node < N_NODES)
          out[OFF_Z + (size_t)node * (KF * HID) + col] = zn;
        dmt = fmaxf(dmt, zn);
      }
      dmt = fmaxf(dmt, __shfl_xor(dmt, 16, 64));
      dmt = fmaxf(dmt, __shfl_xor(dmt, 32, 64));
      if (lg == 0) dred[w][col] = dmt;
    }
  }
  __syncthreads();
  {
    const float m = fmaxf(fmaxf(dred[0][tid], dred[1][tid]),
                          fmaxf(dred[2][tid], dred[3][tid]));
    atomicMax((unsigned int*)(out + OFF_DISEN + tid), __float_as_uint(m));
  }
}

// ---------------------------------------------------------------------------
// pq via MFMA -> biased-uint8 P/Q with per-row scales (r15 verbatim).
// Row layout byte[lc*4+t] = col[t*16+lc] (fixed permutation; W2 matched).
// ---------------------------------------------------------------------------
__global__ __launch_bounds__(256) void pq_mfma_kernel3(
    const float* __restrict__ Z, const float* __restrict__ b1,
    const __bf16* __restrict__ Wpq, unsigned char* __restrict__ P8,
    unsigned char* __restrict__ Q8, float* __restrict__ Psc,
    float* __restrict__ Qsc) {
  const int tid = threadIdx.x;
  const int w = tid >> 6, l = tid & 63;
  const int lg = l >> 4, lc = l & 15;
  const int base = blockIdx.x * 64;              // exact: 3125*64 = 200000
  const int rowA = base + w * 16 + lc;

  bf16x8 af[2];
#pragma unroll
  for (int kh = 0; kh < 2; ++kh) {
    const float4* zp = (const float4*)(Z + (size_t)rowA * HID + kh * 32 + lg * 8);
    const float4 f0 = zp[0], f1 = zp[1];
    bf16x8 a;
    a[0] = (__bf16)f0.x; a[1] = (__bf16)f0.y;
    a[2] = (__bf16)f0.z; a[3] = (__bf16)f0.w;
    a[4] = (__bf16)f1.x; a[5] = (__bf16)f1.y;
    a[6] = (__bf16)f1.z; a[7] = (__bf16)f1.w;
    af[kh] = a;
  }

  f32x4 acc[8];
#pragma unroll
  for (int t = 0; t < 8; ++t) acc[t] = (f32x4){0.f, 0.f, 0.f, 0.f};

#pragma unroll
  for (int t = 0; t < 8; ++t)
#pragma unroll
    for (int kh = 0; kh < 2; ++kh) {
      const bf16x8 bf =
          *(const bf16x8*)(Wpq + ((t * 2 + kh) * 4 + lg) * 128 + lc * 8);
      acc[t] = __builtin_amdgcn_mfma_f32_16x16x32_bf16(af[kh], bf, acc[t],
                                                       0, 0, 0);
    }

  float pvv[4][4], qvv[4][4];
#pragma unroll
  for (int t = 0; t < 4; ++t) {
    const float bias = b1[t * 16 + lc];
#pragma unroll
    for (int r = 0; r < 4; ++r) {
      pvv[t][r] = acc[t][r] + bias;
      qvv[t][r] = acc[t + 4][r];
    }
  }

#pragma unroll
  for (int r = 0; r < 4; ++r) {
    float pm = fmaxf(fmaxf(fabsf(pvv[0][r]), fabsf(pvv[1][r])),
                     fmaxf(fabsf(pvv[2][r]), fabsf(pvv[3][r])));
    float qm = fmaxf(fmaxf(fabsf(qvv[0][r]), fabsf(qvv[1][r])),
                     fmaxf(fabsf(qvv[2][r]), fabsf(qvv[3][r])));
#pragma unroll
    for (int d = 1; d < 16; d <<= 1) {           // 16-lane row reduce
      pm = fmaxf(pm, __shfl_xor(pm, d, 64));
      qm = fmaxf(qm, __shfl_xor(qm, d, 64));
    }
    pm = fmaxf(pm, 1e-12f);
    qm = fmaxf(qm, 1e-12f);
    const float pinv = 127.f / pm, qinv = 127.f / qm;

    uint_t packP = 0, packQ = 0;
#pragma unroll
    for (int t = 0; t < 4; ++t) {
      const int qp = __float2int_rn(pvv[t][r] * pinv) + 128;  // biased uint8
      const int qq = __float2int_rn(qvv[t][r] * qinv) + 128;
      packP |= (uint_t)(qp & 0xff) << (8 * t);
      packQ |= (uint_t)(qq & 0xff) << (8 * t);
    }
    const int grow = base + w * 16 + lg * 4 + r;
    *(uint_t*)(P8 + (size_t)grow * 64 + lc * 4) = packP;
    *(uint_t*)(Q8 + (size_t)grow * 64 + lc * 4) = packQ;
    if (lc == 0) {
      Psc[grow] = pm * (1.f / 127.f);
      Qsc[grow] = qm * (1.f / 127.f);
    }
  }
}

// ---------------------------------------------------------------------------
// Edge kernel v8: 4 edges per wave-step. Lane l: group g=l>>4 owns edge
// (i*4+g); sub=l&15 selects 16 bytes of the 256B node block (k=sub>>2,
// quarter j=sub&3). ONE uint4 load per lane covers P of 4 edges (2nd for
// Q) -> VMEM instrs/edge 8->2, DS reduce 4-stage/16-lane -> 2-stage/4-lane.
// dword d of the uint4 holds cols {b*16 + j*4 + d, b=0..3}; W2 coefs
// preloaded as w2r[d][b]=W2[b*16+j*4+d].
// ---------------------------------------------------------------------------
__global__ __launch_bounds__(256) void edge_kernel8(
    const int* __restrict__ ei, const float* __restrict__ W2,
    const float* __restrict__ b2, const unsigned char* __restrict__ P8,
    const unsigned char* __restrict__ Q8, const float* __restrict__ Psc,
    const float* __restrict__ Qsc, float* __restrict__ ehf,
    float* __restrict__ ehall) {
  __shared__ float tile[4][KF][EPW + 1];
  const int tid = threadIdx.x;
  const int w = tid >> 6;
  const int lane = tid & 63;
  const int g = lane >> 4;          // edge subgroup 0..3
  const int sub = lane & 15;        // 16B chunk within 256B node block
  const int k = sub >> 2;           // k-factor
  const int j = sub & 3;            // quarter within k-row
  const int eb = blockIdx.x * 256 + w * EPW;

  float w2r[4][4];                  // [d][b] = W2[b*16 + j*4 + d]
#pragma unroll
  for (int b = 0; b < 4; ++b) {
    const float4 f = *(const float4*)(W2 + b * 16 + j * 4);
    w2r[0][b] = f.x; w2r[1][b] = f.y; w2r[2][b] = f.z; w2r[3][b] = f.w;
  }
  const float bias2 = b2[0];

  const int srcl = ei[eb + lane];                  // coalesced
  const int dstl = ei[E_EDGES + eb + lane];

  uint4 pv[EPIPE], qv[EPIPE];
  float ps[EPIPE], qs[EPIPE];
#pragma unroll
  for (int d = 0; d < EPIPE; ++d) {
    const int s = __shfl(srcl, d * 4 + g, 64);     // bpermute (g varies)
    const int t = __shfl(dstl, d * 4 + g, 64);
    pv[d] = *(const uint4*)(P8 + (size_t)s * 256 + sub * 16);
    qv[d] = *(const uint4*)(Q8 + (size_t)t * 256 + sub * 16);
    ps[d] = Psc[s * 4 + k];
    qs[d] = Qsc[t * 4 + k];
  }

#pragma unroll
  for (int i = 0; i < 16; ++i) {                   // 16 steps x 4 edges
    const uint4 p = pv[i & (EPIPE - 1)];
    const uint4 q = qv[i & (EPIPE - 1)];
    const float pss = ps[i & (EPIPE - 1)], qss = qs[i & (EPIPE - 1)];
    if (i + EPIPE < 16) {                          // static under full unroll
      const int s = __shfl(srcl, (i + EPIPE) * 4 + g, 64);
      const int t = __shfl(dstl, (i + EPIPE) * 4 + g, 64);
      pv[i & (EPIPE - 1)] = *(const uint4*)(P8 + (size_t)s * 256 + sub * 16);
      qv[i & (EPIPE - 1)] = *(const uint4*)(Q8 + (size_t)t * 256 + sub * 16);
      ps[i & (EPIPE - 1)] = Psc[s * 4 + k];
      qs[i & (EPIPE - 1)] = Qsc[t * 4 + k];
    }
    const float c = -128.f * (pss + qss);          // bias fold

    const uint_t pd[4] = {p.x, p.y, p.z, p.w};
    const uint_t qd[4] = {q.x, q.y, q.z, q.w};
    float s4 = 0.f;
#pragma unroll
    for (int d = 0; d < 4; ++d) {
      const float p0 = (float)(pd[d] & 0xffu);
      const float p1 = (float)((pd[d] >> 8) & 0xffu);
      const float p2 = (float)((pd[d] >> 16) & 0xffu);
      const float p3 = (float)(pd[d] >> 24);
      const float q0 = (float)(qd[d] & 0xffu);
      const float q1 = (float)((qd[d] >> 8) & 0xffu);
      const float q2 = (float)((qd[d] >> 16) & 0xffu);
      const float q3 = (float)(qd[d] >> 24);
      s4 = fmaf(fmaxf(fmaf(p0, pss, fmaf(q0, qss, c)), 0.f), w2r[d][0], s4);
      s4 = fmaf(fmaxf(fmaf(p1, pss, fmaf(q1, qss, c)), 0.f), w2r[d][1], s4);
      s4 = fmaf(fmaxf(fmaf(p2, pss, fmaf(q2, qss, c)), 0.f), w2r[d][2], s4);
      s4 = fmaf(fmaxf(fmaf(p3, pss, fmaf(q3, qss, c)), 0.f), w2r[d][3], s4);
    }
    // reduce the 4 quarters (lanes j=0..3 of this (g,k) group)
    s4 += __shfl_xor(s4, 1, 64);
    s4 += __shfl_xor(s4, 2, 64);
    if (j == 0) tile[w][k][i * 4 + g] = s4 + bias2;
  }
  __syncthreads();

  const float v0 = tile[w][0][lane];
  const float v1 = tile[w][1][lane];
  const float v2 = tile[w][2][lane];
  const float v3 = tile[w][3][lane];
  ehall[(size_t)0 * E_EDGES + eb + lane] = v0;     // coalesced per wave
  ehall[(size_t)1 * E_EDGES + eb + lane] = v1;
  ehall[(size_t)2 * E_EDGES + eb + lane] = v2;
  ehall[(size_t)3 * E_EDGES + eb + lane] = v3;
  ehf[eb + lane] = fmaxf(fmaxf(v0, v1), fmaxf(v2, v3));
}

// ---------------------------------------------------------------------------
extern "C" void kernel_launch(void* const* d_in, const int* in_sizes, int n_in,
                              void* d_out, int out_size, void* d_ws,
                              size_t ws_size, hipStream_t stream) {
  const float* x      = (const float*)d_in[0];
  const int*   ei     = (const int*)  d_in[1];
  const float* W_init = (const float*)d_in[2];
  const float* b_init = (const float*)d_in[3];
  const float* W1     = (const float*)d_in[4];
  const float* b1     = (const float*)d_in[5];
  const float* W2     = (const float*)d_in[6];
  const float* b2     = (const float*)d_in[7];
  float* out = (float*)d_out;

  // d_ws: P8 (12.8MB) | Q8 (12.8MB) | Psc (0.8MB) | Qsc (0.8MB) |
  //       Wz (64KB) | Wpq (16KB).  Total ~27.3MB << ws_size.
  unsigned char* P8 = (unsigned char*)d_ws;
  unsigned char* Q8 = P8 + (size_t)NROWS * 64;
  float* Psc = (float*)(Q8 + (size_t)NROWS * 64);
  float* Qsc = Psc + NROWS;
  __bf16* Wz  = (__bf16*)(Qsc + NROWS);
  __bf16* Wpq = Wz + 32768;

  prep_kernel<<<41, 256, 0, stream>>>(W_init, W1, out + OFF_DISEN, Wz, Wpq);
  z_mfma_kernel2<<<(N_NODES + 63) / 64, 256, 0, stream>>>(
      x, b_init, Wz, out);
  pq_mfma_kernel3<<<NROWS / 64, 256, 0, stream>>>(
      out + OFF_Z, b1, Wpq, P8, Q8, Psc, Qsc);
  edge_kernel8<<<E_EDGES / 256, 256, 0, stream>>>(
      ei, W2, b2, P8, Q8, Psc, Qsc, out + OFF_EHF, out + OFF_EHALL);
}

// Round 18
// 128.191 us; speedup vs baseline: 1.0510x; 1.0026x over previous
//
#include <hip/hip_runtime.h>
#include <hip/hip_bf16.h>
#include <math.h>

#define N_NODES 50000
#define E_EDGES 800000
#define IN_DIM  128
#define HID     64
#define KF      4
#define EXP_HID 64

// d_out layout (float32, concatenated in return order):
//   disen_graph_emb (K*HID = 256) | Z (N*K*HID = 12,800,000) |
//   e_h_final (E = 800,000)       | e_h_all (K*E = 3,200,000)
#define OFF_DISEN 0
#define OFF_Z     (KF*HID)
#define OFF_EHF   (OFF_Z + N_NODES*KF*HID)
#define OFF_EHALL (OFF_EHF + E_EDGES)

#define NROWS (N_NODES * KF)     // 200000 (n,k) rows
#define EPW 64                   // edges per wave
#define EPIPE 4                  // pipeline depth in 4-edge steps
#define TPAD 68                  // tile stride: bank = 4k+g, all distinct

typedef __bf16 bf16x8 __attribute__((ext_vector_type(8)));
typedef float  f32x4  __attribute__((ext_vector_type(4)));
typedef float  f32x2  __attribute__((ext_vector_type(2)));
typedef unsigned short ushort_t;
typedef unsigned int   uint_t;

// ---------------------------------------------------------------------------
// prep (r12 verbatim): 41 blocks. 0-31: Wz swizzle; 32-39: Wpq swizzle;
// 40: disen init.
// ---------------------------------------------------------------------------
__global__ __launch_bounds__(256) void prep_kernel(
    const float* __restrict__ W, const float* __restrict__ W1,
    float* __restrict__ disen, __bf16* __restrict__ Wz,
    __bf16* __restrict__ Wpq) {
  const int b = blockIdx.x, tid = threadIdx.x;
  if (b < 32) {
#pragma unroll
    for (int i = 0; i < 4; ++i) {
      const int idx = (b * 4 + i) * 256 + tid;    // k*8192 + ii*64 + h
      const int k  = idx >> 13;
      const int ii = (idx >> 6) & 127;
      const int h  = idx & 63;
      const int col = k * 64 + h;
      const int t = col >> 4, c = col & 15;
      const int kh = ii >> 5, g = (ii >> 3) & 3, e = ii & 7;
      Wz[((t * 4 + kh) * 4 + g) * 128 + c * 8 + e] = (__bf16)W[idx];
    }
  } else if (b < 40) {
#pragma unroll
    for (int i = 0; i < 4; ++i) {
      const int idx = ((b - 32) * 4 + i) * 256 + tid;   // r*64 + cc
      const int r = idx >> 6, cc = idx & 63;
      const int k = (r < 64) ? r : (r - 64);
      const int j = (r < 64) ? cc : (64 + cc);
      const int t = j >> 4, c = j & 15;
      const int kh = k >> 5, g = (k >> 3) & 3, e = k & 7;
      Wpq[((t * 2 + kh) * 4 + g) * 128 + c * 8 + e] = (__bf16)W1[idx];
    }
  } else {
    disen[tid] = 0.f;
  }
}

// ---------------------------------------------------------------------------
// z via MFMA (r13 verbatim, k-phased). Measured-good.
// ---------------------------------------------------------------------------
__global__ __launch_bounds__(256) void z_mfma_kernel2(
    const float* __restrict__ x, const float* __restrict__ b_init,
    const __bf16* __restrict__ Wz, float* __restrict__ out) {
  __shared__ float dred[4][256];
  const int tid = threadIdx.x;
  const int w = tid >> 6, l = tid & 63;
  const int lg = l >> 4, lc = l & 15;
  const int n0 = blockIdx.x * 64;
  const int ra = min(n0 + w * 16 + lc, N_NODES - 1);   // A row (clamped tail)

  bf16x8 af[4];
#pragma unroll
  for (int kh = 0; kh < 4; ++kh) {
    const float4* xp = (const float4*)(x + (size_t)ra * IN_DIM + kh * 32 + lg * 8);
    const float4 f0 = xp[0], f1 = xp[1];
    bf16x8 a;
    a[0] = (__bf16)f0.x; a[1] = (__bf16)f0.y;
    a[2] = (__bf16)f0.z; a[3] = (__bf16)f0.w;
    a[4] = (__bf16)f1.x; a[5] = (__bf16)f1.y;
    a[6] = (__bf16)f1.z; a[7] = (__bf16)f1.w;
    af[kh] = a;
  }

#pragma unroll 1
  for (int k = 0; k < KF; ++k) {
    f32x4 acc[4];
#pragma unroll
    for (int tt = 0; tt < 4; ++tt) acc[tt] = (f32x4){0.f, 0.f, 0.f, 0.f};

#pragma unroll
    for (int tt = 0; tt < 4; ++tt)
#pragma unroll
      for (int kh = 0; kh < 4; ++kh) {
        const bf16x8 bf = *(const bf16x8*)(
            Wz + (((k * 4 + tt) * 4 + kh) * 4 + lg) * 128 + lc * 8);
        acc[tt] = __builtin_amdgcn_mfma_f32_16x16x32_bf16(af[kh], bf, acc[tt],
                                                          0, 0, 0);
      }

    float vals[4][4];
#pragma unroll
    for (int tt = 0; tt < 4; ++tt) {
      const float bias = b_init[(k * 4 + tt) * 16 + lc];
#pragma unroll
      for (int r = 0; r < 4; ++r)
        vals[tt][r] = fmaxf(acc[tt][r] + bias, 0.f);
    }
    float s[4];
#pragma unroll
    for (int r = 0; r < 4; ++r)
      s[r] = vals[0][r] * vals[0][r] + vals[1][r] * vals[1][r] +
             vals[2][r] * vals[2][r] + vals[3][r] * vals[3][r];
#pragma unroll
    for (int d = 1; d < 16; d <<= 1)
#pragma unroll
      for (int r = 0; r < 4; ++r) s[r] += __shfl_xor(s[r], d, 64);
    float rn[4];
#pragma unroll
    for (int r = 0; r < 4; ++r)
      rn[r] = 1.f / fmaxf(sqrtf(s[r]), 1e-12f);

#pragma unroll
    for (int tt = 0; tt < 4; ++tt) {
      const int col = k * 64 + tt * 16 + lc;
      float dmt = 0.f;
#pragma unroll
      for (int r = 0; r < 4; ++r) {
        const float zn = vals[tt][r] * rn[r];
        const int node = n0 + w * 16 + lg * 4 + r;
        if (node < N_NODES)
          out[OFF_Z + (size_t)node * (KF * HID) + col] = zn;
        dmt = fmaxf(dmt, zn);
      }
      dmt = fmaxf(dmt, __shfl_xor(dmt, 16, 64));
      dmt = fmaxf(dmt, __shfl_xor(dmt, 32, 64));
      if (lg == 0) dred[w][col] = dmt;
    }
  }
  __syncthreads();
  {
    const float m = fmaxf(fmaxf(dred[0][tid], dred[1][tid]),
                          fmaxf(dred[2][tid], dred[3][tid]));
    atomicMax((unsigned int*)(out + OFF_DISEN + tid), __float_as_uint(m));
  }
}

// ---------------------------------------------------------------------------
// pq via MFMA -> biased-uint8 P/Q with per-row scales (r15 verbatim).
// Row layout byte[lc*4+t] = col[t*16+lc] (fixed permutation; W2 matched).
// ---------------------------------------------------------------------------
__global__ __launch_bounds__(256) void pq_mfma_kernel3(
    const float* __restrict__ Z, const float* __restrict__ b1,
    const __bf16* __restrict__ Wpq, unsigned char* __restrict__ P8,
    unsigned char* __restrict__ Q8, float* __restrict__ Psc,
    float* __restrict__ Qsc) {
  const int tid = threadIdx.x;
  const int w = tid >> 6, l = tid & 63;
  const int lg = l >> 4, lc = l & 15;
  const int base = blockIdx.x * 64;              // exact: 3125*64 = 200000
  const int rowA = base + w * 16 + lc;

  bf16x8 af[2];
#pragma unroll
  for (int kh = 0; kh < 2; ++kh) {
    const float4* zp = (const float4*)(Z + (size_t)rowA * HID + kh * 32 + lg * 8);
    const float4 f0 = zp[0], f1 = zp[1];
    bf16x8 a;
    a[0] = (__bf16)f0.x; a[1] = (__bf16)f0.y;
    a[2] = (__bf16)f0.z; a[3] = (__bf16)f0.w;
    a[4] = (__bf16)f1.x; a[5] = (__bf16)f1.y;
    a[6] = (__bf16)f1.z; a[7] = (__bf16)f1.w;
    af[kh] = a;
  }

  f32x4 acc[8];
#pragma unroll
  for (int t = 0; t < 8; ++t) acc[t] = (f32x4){0.f, 0.f, 0.f, 0.f};

#pragma unroll
  for (int t = 0; t < 8; ++t)
#pragma unroll
    for (int kh = 0; kh < 2; ++kh) {
      const bf16x8 bf =
          *(const bf16x8*)(Wpq + ((t * 2 + kh) * 4 + lg) * 128 + lc * 8);
      acc[t] = __builtin_amdgcn_mfma_f32_16x16x32_bf16(af[kh], bf, acc[t],
                                                       0, 0, 0);
    }

  float pvv[4][4], qvv[4][4];
#pragma unroll
  for (int t = 0; t < 4; ++t) {
    const float bias = b1[t * 16 + lc];
#pragma unroll
    for (int r = 0; r < 4; ++r) {
      pvv[t][r] = acc[t][r] + bias;
      qvv[t][r] = acc[t + 4][r];
    }
  }

#pragma unroll
  for (int r = 0; r < 4; ++r) {
    float pm = fmaxf(fmaxf(fabsf(pvv[0][r]), fabsf(pvv[1][r])),
                     fmaxf(fabsf(pvv[2][r]), fabsf(pvv[3][r])));
    float qm = fmaxf(fmaxf(fabsf(qvv[0][r]), fabsf(qvv[1][r])),
                     fmaxf(fabsf(qvv[2][r]), fabsf(qvv[3][r])));
#pragma unroll
    for (int d = 1; d < 16; d <<= 1) {           // 16-lane row reduce
      pm = fmaxf(pm, __shfl_xor(pm, d, 64));
      qm = fmaxf(qm, __shfl_xor(qm, d, 64));
    }
    pm = fmaxf(pm, 1e-12f);
    qm = fmaxf(qm, 1e-12f);
    const float pinv = 127.f / pm, qinv = 127.f / qm;

    uint_t packP = 0, packQ = 0;
#pragma unroll
    for (int t = 0; t < 4; ++t) {
      const int qp = __float2int_rn(pvv[t][r] * pinv) + 128;  // biased uint8
      const int qq = __float2int_rn(qvv[t][r] * qinv) + 128;
      packP |= (uint_t)(qp & 0xff) << (8 * t);
      packQ |= (uint_t)(qq & 0xff) << (8 * t);
    }
    const int grow = base + w * 16 + lg * 4 + r;
    *(uint_t*)(P8 + (size_t)grow * 64 + lc * 4) = packP;
    *(uint_t*)(Q8 + (size_t)grow * 64 + lc * 4) = packQ;
    if (lc == 0) {
      Psc[grow] = pm * (1.f / 127.f);
      Qsc[grow] = qm * (1.f / 127.f);
    }
  }
}

// ---------------------------------------------------------------------------
// Edge kernel v9: r17 structure (4 edges/step, uint4 group loads) with
// (a) packed-f32 inner math (float2 ext-vectors -> v_pk_fma_f32/v_pk_max_f32,
//     ~23% fewer VALU instrs in the dequant->relu->dot chain, IEEE fp32);
// (b) tile stride 68 (bank = 4k+g, 16 distinct -> conflict-free writes).
// ---------------------------------------------------------------------------
__global__ __launch_bounds__(256) void edge_kernel9(
    const int* __restrict__ ei, const float* __restrict__ W2,
    const float* __restrict__ b2, const unsigned char* __restrict__ P8,
    const unsigned char* __restrict__ Q8, const float* __restrict__ Psc,
    const float* __restrict__ Qsc, float* __restrict__ ehf,
    float* __restrict__ ehall) {
  __shared__ float tile[4][KF][TPAD];
  const int tid = threadIdx.x;
  const int w = tid >> 6;
  const int lane = tid & 63;
  const int g = lane >> 4;          // edge subgroup 0..3
  const int sub = lane & 15;        // 16B chunk within 256B node block
  const int k = sub >> 2;           // k-factor
  const int j = sub & 3;            // quarter within k-row
  const int eb = blockIdx.x * 256 + w * EPW;

  // dword d covers cols {t*16 + j*4 + d, t=0..3}; pair as (t0,t1)/(t2,t3)
  f32x2 wA[4], wB[4];
#pragma unroll
  for (int t = 0; t < 4; ++t) {
    const float4 f = *(const float4*)(W2 + t * 16 + j * 4);
    // f.{x,y,z,w} = W2[t*16+j*4+{0,1,2,3}] -> distribute over d
    wA[0][t >> 1 ? 0 : 0] = wA[0][0];  // placeholder (overwritten below)
  }
#pragma unroll
  for (int d = 0; d < 4; ++d) {
    const float c0 = W2[0 * 16 + j * 4 + d];
    const float c1 = W2[1 * 16 + j * 4 + d];
    const float c2_ = W2[2 * 16 + j * 4 + d];
    const float c3 = W2[3 * 16 + j * 4 + d];
    wA[d] = (f32x2){c0, c1};
    wB[d] = (f32x2){c2_, c3};
  }
  const float bias2 = b2[0];

  const int srcl = ei[eb + lane];                  // coalesced
  const int dstl = ei[E_EDGES + eb + lane];

  uint4 pv[EPIPE], qv[EPIPE];
  float ps[EPIPE], qs[EPIPE];
#pragma unroll
  for (int d = 0; d < EPIPE; ++d) {
    const int s = __shfl(srcl, d * 4 + g, 64);     // bpermute (g varies)
    const int t = __shfl(dstl, d * 4 + g, 64);
    pv[d] = *(const uint4*)(P8 + (size_t)s * 256 + sub * 16);
    qv[d] = *(const uint4*)(Q8 + (size_t)t * 256 + sub * 16);
    ps[d] = Psc[s * 4 + k];
    qs[d] = Qsc[t * 4 + k];
  }

  const f32x2 zero2 = (f32x2){0.f, 0.f};

#pragma unroll
  for (int i = 0; i < 16; ++i) {                   // 16 steps x 4 edges
    const uint4 p = pv[i & (EPIPE - 1)];
    const uint4 q = qv[i & (EPIPE - 1)];
    const float pss = ps[i & (EPIPE - 1)], qss = qs[i & (EPIPE - 1)];
    if (i + EPIPE < 16) {                          // static under full unroll
      const int s = __shfl(srcl, (i + EPIPE) * 4 + g, 64);
      const int t = __shfl(dstl, (i + EPIPE) * 4 + g, 64);
      pv[i & (EPIPE - 1)] = *(const uint4*)(P8 + (size_t)s * 256 + sub * 16);
      qv[i & (EPIPE - 1)] = *(const uint4*)(Q8 + (size_t)t * 256 + sub * 16);
      ps[i & (EPIPE - 1)] = Psc[s * 4 + k];
      qs[i & (EPIPE - 1)] = Qsc[t * 4 + k];
    }
    const f32x2 ps2 = (f32x2){pss, pss};
    const f32x2 qs2 = (f32x2){qss, qss};
    const float cb = -128.f * (pss + qss);         // bias fold
    const f32x2 c2 = (f32x2){cb, cb};

    const uint_t pd[4] = {p.x, p.y, p.z, p.w};
    const uint_t qd[4] = {q.x, q.y, q.z, q.w};
    f32x2 acc2 = zero2;
#pragma unroll
    for (int d = 0; d < 4; ++d) {
      const f32x2 pa = (f32x2){(float)(pd[d] & 0xffu),
                               (float)((pd[d] >> 8) & 0xffu)};
      const f32x2 pb = (f32x2){(float)((pd[d] >> 16) & 0xffu),
                               (float)(pd[d] >> 24)};
      const f32x2 qa = (f32x2){(float)(qd[d] & 0xffu),
                               (float)((qd[d] >> 8) & 0xffu)};
      const f32x2 qb = (f32x2){(float)((qd[d] >> 16) & 0xffu),
                               (float)(qd[d] >> 24)};
      const f32x2 ra =
          __builtin_elementwise_max(pa * ps2 + (qa * qs2 + c2), zero2);
      const f32x2 rb =
          __builtin_elementwise_max(pb * ps2 + (qb * qs2 + c2), zero2);
      acc2 = ra * wA[d] + acc2;                    // v_pk_fma_f32
      acc2 = rb * wB[d] + acc2;
    }
    float s4 = acc2[0] + acc2[1];
    // reduce the 4 quarters (lanes j=0..3 of this (g,k) group)
    s4 += __shfl_xor(s4, 1, 64);
    s4 += __shfl_xor(s4, 2, 64);
    if (j == 0) tile[w][k][i * 4 + g] = s4 + bias2;
  }
  __syncthreads();

  const float v0 = tile[w][0][lane];
  const float v1 = tile[w][1][lane];
  const float v2 = tile[w][2][lane];
  const float v3 = tile[w][3][lane];
  ehall[(size_t)0 * E_EDGES + eb + lane] = v0;     // coalesced per wave
  ehall[(size_t)1 * E_EDGES + eb + lane] = v1;
  ehall[(size_t)2 * E_EDGES + eb + lane] = v2;
  ehall[(size_t)3 * E_EDGES + eb + lane] = v3;
  ehf[eb + lane] = fmaxf(fmaxf(v0, v1), fmaxf(v2, v3));
}

// ---------------------------------------------------------------------------
extern "C" void kernel_launch(void* const* d_in, const int* in_sizes, int n_in,
                              void* d_out, int out_size, void* d_ws,
                              size_t ws_size, hipStream_t stream) {
  const float* x      = (const float*)d_in[0];
  const int*   ei     = (const int*)  d_in[1];
  const float* W_init = (const float*)d_in[2];
  const float* b_init = (const float*)d_in[3];
  const float* W1     = (const float*)d_in[4];
  const float* b1     = (const float*)d_in[5];
  const float* W2     = (const float*)d_in[6];
  const float* b2     = (const float*)d_in[7];
  float* out = (float*)d_out;

  // d_ws: P8 (12.8MB) | Q8 (12.8MB) | Psc (0.8MB) | Qsc (0.8MB) |
  //       Wz (64KB) | Wpq (16KB).  Total ~27.3MB << ws_size.
  unsigned char* P8 = (unsigned char*)d_ws;
  unsigned char* Q8 = P8 + (size_t)NROWS * 64;
  float* Psc = (float*)(Q8 + (size_t)NROWS * 64);
  float* Qsc = Psc + NROWS;
  __bf16* Wz  = (__bf16*)(Qsc + NROWS);
  __bf16* Wpq = Wz + 32768;

  prep_kernel<<<41, 256, 0, stream>>>(W_init, W1, out + OFF_DISEN, Wz, Wpq);
  z_mfma_kernel2<<<(N_NODES + 63) / 64, 256, 0, stream>>>(
      x, b_init, Wz, out);
  pq_mfma_kernel3<<<NROWS / 64, 256, 0, stream>>>(
      out + OFF_Z, b1, Wpq, P8, Q8, Psc, Qsc);
  edge_kernel9<<<E_EDGES / 256, 256, 0, stream>>>(
      ei, W2, b2, P8, Q8, Psc, Qsc, out + OFF_EHF, out + OFF_EHALL);
}